// Round 17
// baseline (73.706 us; speedup 1.0000x reference)
//
#include <hip/hip_runtime.h>
#include <math.h>

#define NB 16384
typedef _Float16 f16;
typedef _Float16 f16x8 __attribute__((ext_vector_type(8)));
typedef _Float16 f16x4 __attribute__((ext_vector_type(4)));
typedef float f32x4 __attribute__((ext_vector_type(4)));

__device__ __forceinline__ float fast_sig(float v)  { return __builtin_amdgcn_rcpf(1.0f + __expf(-v)); }
__device__ __forceinline__ float fast_tanh(float v) { return 1.0f - 2.0f * __builtin_amdgcn_rcpf(1.0f + __expf(2.0f * v)); }

#define MFMA16(A, B, C) __builtin_amdgcn_mfma_f32_16x16x32_f16(A, B, C, 0, 0, 0)
#define WBAR() __builtin_amdgcn_wave_barrier()

// ---------------- kernel 1: es = mean_L(enc) — measured 30us ≈ BW roofline ------
__global__ __launch_bounds__(256) void es_kernel(
    const float* __restrict__ enc, float* __restrict__ es)
{
    const int u = blockIdx.x * 256 + threadIdx.x;    // float4 unit
    const float4* e4 = (const float4*)enc;
    float ax = 0.f, ay = 0.f, az = 0.f, aw = 0.f;
    #pragma unroll 8
    for (int L = 0; L < 48; ++L) {
        const float4 v = e4[(size_t)L * (NB * 15) + u];
        ax += v.x; ay += v.y; az += v.z; aw += v.w;
    }
    const float s = 1.f / 48.f;
    float4 r; r.x = ax * s; r.y = ay * s; r.z = az * s; r.w = aw * s;
    ((float4*)es)[u] = r;
}

// ---------------- kernel 2: decode — r13 spine/head + shortened phase paths -----
// 1024 blocks x 128 thr (r13 base = best, 67.3us). r13's partition is barrier-
// minimal (out->rin->B and B->h->C each force one cross-wave barrier). This
// round shortens the phase critical paths instead:
//  (1) E fused into D on the head: out = 16-lane DPP xor-reduce of Wf3*relu(z2)
//      -> removes E's LDS round-trip (z2 write + WBAR + read + MFMA).
//  (2) spine preloads xa1 (all spine-written cols) BEFORE the mid-barrier,
//      hiding its latency in the wait-for-head slack; only xa0 (head-written
//      rin cols) loads after the barrier.
// x16 row layout (72 halves): [0..3]=rin [4..33]=enh [34..63]=h [64..71]=scratch
__global__ __launch_bounds__(128, 2) void decoder_kernel(
    const float* __restrict__ y,      // [B,13,4]
    const float* __restrict__ enc,    // [48,B,60]
    const float* __restrict__ esrc,   // [B,60] premeaned (or null -> cold scan)
    const float* __restrict__ hidden, // [B,30]
    const float* __restrict__ Wv,  const float* __restrict__ bv,
    const float* __restrict__ Wg,  const float* __restrict__ bg,
    const float* __restrict__ Wf1, const float* __restrict__ bf1,
    const float* __restrict__ Wf2, const float* __restrict__ bf2,
    const float* __restrict__ Wf3, const float* __restrict__ bf3,
    const float* __restrict__ Wih, const float* __restrict__ bih,
    const float* __restrict__ Whh, const float* __restrict__ bhh,
    float* __restrict__ out)          // [12,B]
{
    __shared__ __align__(16) f16 x16[16][72];   // 2304 B
    __shared__ __align__(16) f16 z1b[16][32];   // 1024 B

    const int t = threadIdx.x;
    const int wid = t >> 6, l = t & 63;
    const int r = l & 15, g = l >> 4;        // A-row / D-col = r; k-block & D-row-group = g
    const int bw = blockIdx.x * 16;          // block's first global batch row
    const f32x4 kz = {0.f, 0.f, 0.f, 0.f};

    // ---- zero LDS (128 threads; x16 = 576 u32, z1b = 256 u32)
    #pragma unroll
    for (int d = 0; d < 5; ++d) { const int u = d * 128 + t; if (u < 576) ((unsigned*)x16)[u] = 0u; }
    #pragma unroll
    for (int d = 0; d < 2; ++d) ((unsigned*)z1b)[d * 128 + t] = 0u;

    // ---- stage es for 16 rows -> x16 (premeaned fast path, or cold scan)
    if (esrc) {
        const float4* s4 = (const float4*)esrc + (size_t)bw * 15;
        #pragma unroll
        for (int s = 0; s < 2; ++s) {
            const int u = s * 128 + t;               // 240 float4 units
            if (u < 240) {
                const float4 v = s4[u];
                const int row = u / 15, q4 = u - row * 15;
                f16x4 h = {(f16)v.x, (f16)v.y, (f16)v.z, (f16)v.w};
                *(f16x4*)&x16[row][q4 * 4] = h;
            }
        }
    } else {   // cold correctness path (ws too small)
        const float4* e4 = (const float4*)enc + (size_t)bw * 15;
        const float sc = 1.f / 48.f;
        #pragma unroll 1
        for (int s = 0; s < 2; ++s) {
            const int u = s * 128 + t;
            if (u < 240) {
                const int row = u / 15, q4 = u - row * 15;
                float ax = 0.f, ay = 0.f, az = 0.f, aw = 0.f;
                for (int L = 0; L < 48; ++L) {
                    const float4 v = e4[(size_t)L * (NB * 15) + u];
                    ax += v.x; ay += v.y; az += v.z; aw += v.w;
                }
                f16x4 h = {(f16)(ax*sc), (f16)(ay*sc), (f16)(az*sc), (f16)(aw*sc)};
                *(f16x4*)&x16[row][q4 * 4] = h;
            }
        }
    }

    // ---- per-wave weight fragments (B-frag elem e of lane l = W[kt*32+g*8+e][nt*16+r])
    f16x8 lf[2][8], gf[2][2], f1f[2], f2f;
    float bl[8], bgv[2], bf1v[2], wf1se[2], bf2v = 0.f, bf3v = 0.f, wf3r = 0.f;
    float hD[2][4], VD[2][4], c[2][4] = {};
    float r0v[4] = {0.f, 0.f, 0.f, 0.f};     // head: rin0 staged in REGISTERS

    if (wid == 0) {      // spine: LSTM + gate weights; h0 -> REGISTERS only
        #pragma unroll
        for (int kt = 0; kt < 2; ++kt)
            #pragma unroll
            for (int tq = 0; tq < 8; ++tq) {
                const int gate = tq >> 1, j = (tq & 1) * 16 + r;
                const int trow = gate * 30 + j;
                f16x8 w;
                #pragma unroll
                for (int e = 0; e < 8; ++e) {
                    const int k = kt * 32 + g * 8 + e;
                    float val = 0.f;
                    if (j < 30) val = (k < 34) ? Wih[trow * 34 + k] : Whh[trow * 30 + (k - 34)];
                    w[e] = (f16)val;
                }
                lf[kt][tq] = w;
            }
        #pragma unroll
        for (int nt = 0; nt < 2; ++nt) {
            const int j = nt * 16 + r;
            f16x8 w0, w1;
            #pragma unroll
            for (int e = 0; e < 8; ++e) {
                const int kl = g * 8 + e;
                w0[e] = (f16)((j < 30 && kl >= 2) ? Wg[j * 60 + (kl - 2)] : 0.f);
                w1[e] = (f16)((j < 30 && kl < 30) ? Wg[j * 60 + 30 + kl] : 0.f);
            }
            gf[0][nt] = w0; gf[1][nt] = w1;
        }
        #pragma unroll
        for (int tq = 0; tq < 8; ++tq) {
            const int gate = tq >> 1, j = (tq & 1) * 16 + r;
            bl[tq] = (j < 30) ? bih[gate * 30 + j] + bhh[gate * 30 + j] : 0.f;
        }
        #pragma unroll
        for (int nt = 0; nt < 2; ++nt) {
            const int j = nt * 16 + r;
            bgv[nt] = (j < 30) ? bg[j] : 0.f;
        }
        #pragma unroll
        for (int nt = 0; nt < 2; ++nt)       // h0 -> registers (x16 write deferred!)
            #pragma unroll
            for (int q = 0; q < 4; ++q) {
                const int row = 4 * g + q, j = nt * 16 + r;
                hD[nt][q] = (j < 30) ? hidden[(size_t)(bw + row) * 30 + j] : 0.f;
            }
    } else {             // head: fc weights; rin0 -> registers (x16 write deferred!)
        #pragma unroll
        for (int nt = 0; nt < 2; ++nt) {
            const int j = nt * 16 + r;
            f16x8 w;
            #pragma unroll
            for (int e = 0; e < 8; ++e) {
                const int kl = g * 8 + e;
                w[e] = (f16)((j < 30 && kl >= 2) ? Wf1[j * 31 + (kl - 2)] : 0.f);
            }
            f1f[nt] = w;
            bf1v[nt]  = (j < 30) ? bf1[j] : 0.f;
            wf1se[nt] = (j < 30) ? Wf1[j * 31 + 30] : 0.f;
        }
        #pragma unroll
        for (int e = 0; e < 8; ++e) {
            const int kl = g * 8 + e;
            f2f[e] = (f16)((r < 15 && kl < 30) ? Wf2[r * 30 + kl] : 0.f);
        }
        bf2v = (r < 15) ? bf2[r] : 0.f;
        bf3v = bf3[0];
        wf3r = (r < 15) ? Wf3[r] : 0.f;      // E fused into D: scalar per-lane Wf3
        if (l < 16) {    // rin0 = nan_to_num(y[:,0,:]) -> registers
            const float* yp = y + (size_t)(bw + l) * 52;
            #pragma unroll
            for (int d = 0; d < 4; ++d) {
                float v = yp[d];
                r0v[d] = (v == v) ? v : 0.f;
            }
        }
    }
    __syncthreads();     // es fully staged & visible

    // ---- V = es @ Wv.T + bv (spine; vf TRANSIENT; reads es BEFORE x16 reuse)
    f16x8 va;
    if (wid == 0) {
        float bv0 = bv[r];
        float bv1 = (16 + r < 30) ? bv[16 + r] : 0.f;
        f32x4 vd0 = kz, vd1 = kz;
        #pragma unroll
        for (int kt = 0; kt < 2; ++kt) {
            const f16x8 ea = *(const f16x8*)((const char*)x16 + (size_t)r * 144 + kt * 64 + g * 16);
            #pragma unroll
            for (int nt = 0; nt < 2; ++nt) {
                const int j = nt * 16 + r;
                f16x8 w;
                #pragma unroll
                for (int e = 0; e < 8; ++e) {
                    const int kl = kt * 32 + g * 8 + e;
                    w[e] = (f16)((j < 30 && kl < 60) ? Wv[j * 60 + kl] : 0.f);
                }
                if (nt == 0) vd0 = MFMA16(ea, w, vd0); else vd1 = MFMA16(ea, w, vd1);
            }
        }
        #pragma unroll
        for (int q = 0; q < 4; ++q) { VD[0][q] = vd0[q] + bv0; VD[1][q] = vd1[q] + bv1; }
        #pragma unroll
        for (int nt = 0; nt < 2; ++nt)
            #pragma unroll
            for (int q = 0; q < 4; ++q)
                z1b[4 * g + q][nt * 16 + r] = (f16)VD[nt][q];
        WBAR();
        va = *(const f16x8*)((const char*)z1b + (size_t)r * 64 + g * 16);
    }
    __syncthreads();     // es reads drained -> es region may be reused

    // ---- NOW overwrite the es region: h0 (spine, cols 34..63), rin0 (head, 0..3)
    if (wid == 0) {
        #pragma unroll
        for (int nt = 0; nt < 2; ++nt)
            #pragma unroll
            for (int q = 0; q < 4; ++q)
                x16[4 * g + q][34 + nt * 16 + r] = (f16)hD[nt][q];  // nt1 r>=14 -> scratch
    } else {
        if (l < 16) {
            #pragma unroll
            for (int d = 0; d < 4; ++d)
                x16[l][d] = (f16)r0v[d];
        }
    }
    // spine's A_1 reads its own h0 writes (same-wave order); head's rin0 is
    // consumed by B_1 only after the P1-end __syncthreads -> no barrier needed.

    // ---- 12-step pipelined recurrence ------------------------------------------
    float py1 = 0.f, py2 = 0.f, py3 = 0.f;   // head's y prefetch
    f16x8 xa1pre;                             // spine: B's tile-1 operand, preloaded
    #pragma unroll 1
    for (int i = 1; i <= 12; ++i) {
        // P1: spine A_i  ||  head C + fused D/E of step i-1
        if (wid == 0) {
            // A: gate = sig([h|V] @ Wg.T + bg); enh -> x16 cols 4..33
            // (cols 32,33 stale values are zero-weighted in gf[0])
            const f16x8 xhg = *(const f16x8*)((const char*)x16 + (size_t)r * 144 + 64 + g * 16);
            f32x4 gd0 = MFMA16(xhg, gf[0][0], kz); gd0 = MFMA16(va, gf[1][0], gd0);
            f32x4 gd1 = MFMA16(xhg, gf[0][1], kz); gd1 = MFMA16(va, gf[1][1], gd1);
            #pragma unroll
            for (int nt = 0; nt < 2; ++nt)
                #pragma unroll
                for (int q = 0; q < 4; ++q) {
                    const float a  = (nt ? gd1[q] : gd0[q]) + bgv[nt];
                    const float gt = fast_sig(a);
                    const float enh = gt * hD[nt][q] + (1.f - gt) * VD[nt][q];
                    const int j = nt * 16 + r;
                    if (j < 30) x16[4 * g + q][4 + j] = (f16)enh;
                }
            WBAR();
            // preload B's tile-1 operand: cols 32..63 are ALL spine-written
            // (own enh[28,29] just stored + own h from B_{i-1}) -> safe before
            // the barrier; latency hides in the wait-for-head slack.
            xa1pre = *(const f16x8*)((const char*)x16 + (size_t)r * 144 + 64 + g * 16);
        } else if (i > 1) {
            const int s = i - 1;
            const float se = (float)s * (1.f / 12.f);
            // C: z1 = relu([h_s|se] @ Wf1.T + bf1)  (concurrent cols 32/33 writes
            // by spine A are finite f16 and zero-weighted in f1f -> safe)
            {
                const f16x8 hn = *(const f16x8*)((const char*)x16 + (size_t)r * 144 + 64 + g * 16);
                f32x4 d0 = MFMA16(hn, f1f[0], kz);
                f32x4 d1 = MFMA16(hn, f1f[1], kz);
                #pragma unroll
                for (int nt = 0; nt < 2; ++nt)
                    #pragma unroll
                    for (int q = 0; q < 4; ++q) {
                        const float z = fmaxf((nt ? d1[q] : d0[q]) + bf1v[nt] + se * wf1se[nt], 0.f);
                        z1b[4 * g + q][nt * 16 + r] = (f16)z;
                    }
            }
            WBAR();
            // D + fused E: z2 stays in f32 regs; out = DPP xor-reduce over the
            // 16-lane r-group of Wf3[r]*relu(z2) (masks 1,2,4,8 stay within g).
            {
                const f16x8 z1a = *(const f16x8*)((const char*)z1b + (size_t)r * 64 + g * 16);
                f32x4 d = MFMA16(z1a, f2f, kz);
                #pragma unroll
                for (int q = 0; q < 4; ++q) {
                    float p = wf3r * fmaxf(d[q] + bf2v, 0.f);
                    p += __shfl_xor(p, 1);
                    p += __shfl_xor(p, 2);
                    p += __shfl_xor(p, 4);
                    p += __shfl_xor(p, 8);
                    if (r == 0) {
                        const float o = p + bf3v;
                        out[(size_t)(s - 1) * NB + bw + 4 * g + q] = o;
                        x16[4 * g + q][3] = (f16)o;      // rin[3] = out
                    }
                }
            }
            if (l < 16) {                                 // rin[0..2] = y[:,s,1:4]
                x16[l][0] = (f16)py1;
                x16[l][1] = (f16)py2;
                x16[l][2] = (f16)py3;
            }
        }
        __syncthreads();   // h_{i-1}+enh_i+rin_i all settled for B_i

        // P2: spine B_i (xa1 preloaded; only xa0 after barrier) || head y-prefetch
        if (wid == 0) {
            const f16x8 xa0 = *(const f16x8*)((const char*)x16 + (size_t)r * 144 + g * 16);
            f32x4 ld[8];
            #pragma unroll
            for (int tq = 0; tq < 8; ++tq) {
                ld[tq] = MFMA16(xa0, lf[0][tq], kz);
                ld[tq] = MFMA16(xa1pre, lf[1][tq], ld[tq]);
            }
            #pragma unroll
            for (int jh = 0; jh < 2; ++jh)
                #pragma unroll
                for (int q = 0; q < 4; ++q) {
                    const float ii = fast_sig (ld[0 + jh][q] + bl[0 + jh]);
                    const float ff = fast_sig (ld[2 + jh][q] + bl[2 + jh]);
                    const float gg = fast_tanh(ld[4 + jh][q] + bl[4 + jh]);
                    const float oo = fast_sig (ld[6 + jh][q] + bl[6 + jh]);
                    const float cn = ff * c[jh][q] + ii * gg;
                    c[jh][q] = cn;
                    const float hn = oo * fast_tanh(cn);
                    hD[jh][q] = hn;
                    x16[4 * g + q][34 + jh * 16 + r] = (f16)hn;  // jh1 r>=14 -> scratch
                }
        } else {
            if (l < 16) {
                const float* yp = y + (size_t)(bw + l) * 52 + (size_t)i * 4;
                py1 = yp[1]; py2 = yp[2]; py3 = yp[3];
            }
        }
        __syncthreads();   // h_i visible for head's CDE_i and spine's A_{i+1}
    }

    // ---- epilogue: head finishes C + fused D/E of step 12
    if (wid == 1) {
        const float se = 1.0f;
        {
            const f16x8 hn = *(const f16x8*)((const char*)x16 + (size_t)r * 144 + 64 + g * 16);
            f32x4 d0 = MFMA16(hn, f1f[0], kz);
            f32x4 d1 = MFMA16(hn, f1f[1], kz);
            #pragma unroll
            for (int nt = 0; nt < 2; ++nt)
                #pragma unroll
                for (int q = 0; q < 4; ++q) {
                    const float z = fmaxf((nt ? d1[q] : d0[q]) + bf1v[nt] + se * wf1se[nt], 0.f);
                    z1b[4 * g + q][nt * 16 + r] = (f16)z;
                }
        }
        WBAR();
        {
            const f16x8 z1a = *(const f16x8*)((const char*)z1b + (size_t)r * 64 + g * 16);
            f32x4 d = MFMA16(z1a, f2f, kz);
            #pragma unroll
            for (int q = 0; q < 4; ++q) {
                float p = wf3r * fmaxf(d[q] + bf2v, 0.f);
                p += __shfl_xor(p, 1);
                p += __shfl_xor(p, 2);
                p += __shfl_xor(p, 4);
                p += __shfl_xor(p, 8);
                if (r == 0)
                    out[(size_t)11 * NB + bw + 4 * g + q] = p + bf3v;
            }
        }
    }
}

extern "C" void kernel_launch(void* const* d_in, const int* in_sizes, int n_in,
                              void* d_out, int out_size, void* d_ws, size_t ws_size,
                              hipStream_t stream) {
    (void)in_sizes; (void)n_in; (void)out_size;
    // 0 batch_ids, 1 y, 2 encoder_outputs, 3 hidden, 4 Wq, 5 bq, 6 Wk, 7 bk,
    // 8 Wv, 9 bv, 10 Wsa1, 11 bsa1, 12 Wsa2, 13 bsa2, 14 Wg, 15 bg,
    // 16 Wf1, 17 bf1, 18 Wf2, 19 bf2, 20 Wf3, 21 bf3, 22 W_ih, 23 b_ih,
    // 24 W_hh, 25 b_hh.  (Wq/bq/Wk/bk/Wsa* dead: softmax over size-1 axis == 1)
    const float* enc = (const float*)d_in[2];
    const size_t es_bytes = (size_t)NB * 60 * sizeof(float);
    float* es = (ws_size >= es_bytes) ? (float*)d_ws : nullptr;

    if (es) {
        es_kernel<<<dim3(NB * 15 / 256), dim3(256), 0, stream>>>(enc, es);
    }
    decoder_kernel<<<dim3(NB / 16), dim3(128), 0, stream>>>(
        (const float*)d_in[1],  enc, es, (const float*)d_in[3],
        (const float*)d_in[8],  (const float*)d_in[9],
        (const float*)d_in[14], (const float*)d_in[15],
        (const float*)d_in[16], (const float*)d_in[17],
        (const float*)d_in[18], (const float*)d_in[19],
        (const float*)d_in[20], (const float*)d_in[21],
        (const float*)d_in[22], (const float*)d_in[23],
        (const float*)d_in[24], (const float*)d_in[25],
        (float*)d_out);
}

// Round 18
// 67.313 us; speedup vs baseline: 1.0950x; 1.0950x over previous
//
#include <hip/hip_runtime.h>
#include <math.h>

#define NB 16384
typedef _Float16 f16;
typedef _Float16 f16x8 __attribute__((ext_vector_type(8)));
typedef _Float16 f16x4 __attribute__((ext_vector_type(4)));
typedef float f32x4 __attribute__((ext_vector_type(4)));

__device__ __forceinline__ float fast_sig(float v)  { return __builtin_amdgcn_rcpf(1.0f + __expf(-v)); }
__device__ __forceinline__ float fast_tanh(float v) { return 1.0f - 2.0f * __builtin_amdgcn_rcpf(1.0f + __expf(2.0f * v)); }

#define MFMA16(A, B, C) __builtin_amdgcn_mfma_f32_16x16x32_f16(A, B, C, 0, 0, 0)
#define WBAR() __builtin_amdgcn_wave_barrier()

// ---------------- kernel 1: es = mean_L(enc) — measured 30us ≈ BW roofline ------
__global__ __launch_bounds__(256) void es_kernel(
    const float* __restrict__ enc, float* __restrict__ es)
{
    const int u = blockIdx.x * 256 + threadIdx.x;    // float4 unit
    const float4* e4 = (const float4*)enc;
    float ax = 0.f, ay = 0.f, az = 0.f, aw = 0.f;
    #pragma unroll 8
    for (int L = 0; L < 48; ++L) {
        const float4 v = e4[(size_t)L * (NB * 15) + u];
        ax += v.x; ay += v.y; az += v.z; aw += v.w;
    }
    const float s = 1.f / 48.f;
    float4 r; r.x = ax * s; r.y = ay * s; r.z = az * s; r.w = aw * s;
    ((float4*)es)[u] = r;
}

// ---------------- kernel 2: decode — spine/head pipeline, 1 tile/block ----------
// r13 configuration, byte-identical — the session's empirical optimum (67.3us).
// Five structural probes regressed vs this: 8-row blocks w/ reg diet (+49us,
// spill), 8-row w/ LDS weights (+20.6), split-B 3-barrier (+2.7), fused-E DPP
// reduce + xa1 preload (+6.4). 1024 blocks x 128 thr (2 waves), one 16-row
// MFMA tile per block -> 8 waves/CU = 2 phase-shifted spine/head pairs per
// SIMD hiding each other's stalls.
// wave0 "spine": A_i ; B_i.  wave1 "head": C/D/E of step i-1 (|| A_i).
// x16 row layout (72 halves): [0..3]=rin [4..33]=enh [34..63]=h [64..71]=scratch
__global__ __launch_bounds__(128, 2) void decoder_kernel(
    const float* __restrict__ y,      // [B,13,4]
    const float* __restrict__ enc,    // [48,B,60]
    const float* __restrict__ esrc,   // [B,60] premeaned (or null -> cold scan)
    const float* __restrict__ hidden, // [B,30]
    const float* __restrict__ Wv,  const float* __restrict__ bv,
    const float* __restrict__ Wg,  const float* __restrict__ bg,
    const float* __restrict__ Wf1, const float* __restrict__ bf1,
    const float* __restrict__ Wf2, const float* __restrict__ bf2,
    const float* __restrict__ Wf3, const float* __restrict__ bf3,
    const float* __restrict__ Wih, const float* __restrict__ bih,
    const float* __restrict__ Whh, const float* __restrict__ bhh,
    float* __restrict__ out)          // [12,B]
{
    __shared__ __align__(16) f16 x16[16][72];   // 2304 B
    __shared__ __align__(16) f16 z1b[16][32];   // 1024 B

    const int t = threadIdx.x;
    const int wid = t >> 6, l = t & 63;
    const int r = l & 15, g = l >> 4;        // A-row / D-col = r; k-block & D-row-group = g
    const int bw = blockIdx.x * 16;          // block's first global batch row
    const f32x4 kz = {0.f, 0.f, 0.f, 0.f};

    // ---- zero LDS (128 threads; x16 = 576 u32, z1b = 256 u32)
    #pragma unroll
    for (int d = 0; d < 5; ++d) { const int u = d * 128 + t; if (u < 576) ((unsigned*)x16)[u] = 0u; }
    #pragma unroll
    for (int d = 0; d < 2; ++d) ((unsigned*)z1b)[d * 128 + t] = 0u;

    // ---- stage es for 16 rows -> x16 (premeaned fast path, or cold scan)
    if (esrc) {
        const float4* s4 = (const float4*)esrc + (size_t)bw * 15;
        #pragma unroll
        for (int s = 0; s < 2; ++s) {
            const int u = s * 128 + t;               // 240 float4 units
            if (u < 240) {
                const float4 v = s4[u];
                const int row = u / 15, q4 = u - row * 15;
                f16x4 h = {(f16)v.x, (f16)v.y, (f16)v.z, (f16)v.w};
                *(f16x4*)&x16[row][q4 * 4] = h;
            }
        }
    } else {   // cold correctness path (ws too small)
        const float4* e4 = (const float4*)enc + (size_t)bw * 15;
        const float sc = 1.f / 48.f;
        #pragma unroll 1
        for (int s = 0; s < 2; ++s) {
            const int u = s * 128 + t;
            if (u < 240) {
                const int row = u / 15, q4 = u - row * 15;
                float ax = 0.f, ay = 0.f, az = 0.f, aw = 0.f;
                for (int L = 0; L < 48; ++L) {
                    const float4 v = e4[(size_t)L * (NB * 15) + u];
                    ax += v.x; ay += v.y; az += v.z; aw += v.w;
                }
                f16x4 h = {(f16)(ax*sc), (f16)(ay*sc), (f16)(az*sc), (f16)(aw*sc)};
                *(f16x4*)&x16[row][q4 * 4] = h;
            }
        }
    }

    // ---- per-wave weight fragments (B-frag elem e of lane l = W[kt*32+g*8+e][nt*16+r])
    f16x8 lf[2][8], gf[2][2], f1f[2], f2f, f3f;
    float bl[8], bgv[2], bf1v[2], wf1se[2], bf2v = 0.f, bf3v = 0.f;
    float hD[2][4], VD[2][4], c[2][4] = {};
    float r0v[4] = {0.f, 0.f, 0.f, 0.f};     // head: rin0 staged in REGISTERS

    if (wid == 0) {      // spine: LSTM + gate weights; h0 -> REGISTERS only
        #pragma unroll
        for (int kt = 0; kt < 2; ++kt)
            #pragma unroll
            for (int tq = 0; tq < 8; ++tq) {
                const int gate = tq >> 1, j = (tq & 1) * 16 + r;
                const int trow = gate * 30 + j;
                f16x8 w;
                #pragma unroll
                for (int e = 0; e < 8; ++e) {
                    const int k = kt * 32 + g * 8 + e;
                    float val = 0.f;
                    if (j < 30) val = (k < 34) ? Wih[trow * 34 + k] : Whh[trow * 30 + (k - 34)];
                    w[e] = (f16)val;
                }
                lf[kt][tq] = w;
            }
        #pragma unroll
        for (int nt = 0; nt < 2; ++nt) {
            const int j = nt * 16 + r;
            f16x8 w0, w1;
            #pragma unroll
            for (int e = 0; e < 8; ++e) {
                const int kl = g * 8 + e;
                w0[e] = (f16)((j < 30 && kl >= 2) ? Wg[j * 60 + (kl - 2)] : 0.f);
                w1[e] = (f16)((j < 30 && kl < 30) ? Wg[j * 60 + 30 + kl] : 0.f);
            }
            gf[0][nt] = w0; gf[1][nt] = w1;
        }
        #pragma unroll
        for (int tq = 0; tq < 8; ++tq) {
            const int gate = tq >> 1, j = (tq & 1) * 16 + r;
            bl[tq] = (j < 30) ? bih[gate * 30 + j] + bhh[gate * 30 + j] : 0.f;
        }
        #pragma unroll
        for (int nt = 0; nt < 2; ++nt) {
            const int j = nt * 16 + r;
            bgv[nt] = (j < 30) ? bg[j] : 0.f;
        }
        #pragma unroll
        for (int nt = 0; nt < 2; ++nt)       // h0 -> registers (x16 write deferred!)
            #pragma unroll
            for (int q = 0; q < 4; ++q) {
                const int row = 4 * g + q, j = nt * 16 + r;
                hD[nt][q] = (j < 30) ? hidden[(size_t)(bw + row) * 30 + j] : 0.f;
            }
    } else {             // head: fc weights; rin0 -> registers (x16 write deferred!)
        #pragma unroll
        for (int nt = 0; nt < 2; ++nt) {
            const int j = nt * 16 + r;
            f16x8 w;
            #pragma unroll
            for (int e = 0; e < 8; ++e) {
                const int kl = g * 8 + e;
                w[e] = (f16)((j < 30 && kl >= 2) ? Wf1[j * 31 + (kl - 2)] : 0.f);
            }
            f1f[nt] = w;
            bf1v[nt]  = (j < 30) ? bf1[j] : 0.f;
            wf1se[nt] = (j < 30) ? Wf1[j * 31 + 30] : 0.f;
        }
        #pragma unroll
        for (int e = 0; e < 8; ++e) {
            const int kl = g * 8 + e;
            f2f[e] = (f16)((r < 15 && kl < 30) ? Wf2[r * 30 + kl] : 0.f);
            f3f[e] = (f16)((r == 0 && kl < 15) ? Wf3[kl] : 0.f);
        }
        bf2v = (r < 15) ? bf2[r] : 0.f;
        bf3v = bf3[0];
        if (l < 16) {    // rin0 = nan_to_num(y[:,0,:]) -> registers
            const float* yp = y + (size_t)(bw + l) * 52;
            #pragma unroll
            for (int d = 0; d < 4; ++d) {
                float v = yp[d];
                r0v[d] = (v == v) ? v : 0.f;
            }
        }
    }
    __syncthreads();     // es fully staged & visible

    // ---- V = es @ Wv.T + bv (spine; reads x16 es cols 0..63 BEFORE any reuse)
    f16x8 va;
    if (wid == 0) {
        float bv0 = bv[r];
        float bv1 = (16 + r < 30) ? bv[16 + r] : 0.f;
        f32x4 vd0 = kz, vd1 = kz;
        #pragma unroll
        for (int kt = 0; kt < 2; ++kt) {
            const f16x8 ea = *(const f16x8*)((const char*)x16 + (size_t)r * 144 + kt * 64 + g * 16);
            #pragma unroll
            for (int nt = 0; nt < 2; ++nt) {
                const int j = nt * 16 + r;
                f16x8 w;
                #pragma unroll
                for (int e = 0; e < 8; ++e) {
                    const int kl = kt * 32 + g * 8 + e;
                    w[e] = (f16)((j < 30 && kl < 60) ? Wv[j * 60 + kl] : 0.f);
                }
                if (nt == 0) vd0 = MFMA16(ea, w, vd0); else vd1 = MFMA16(ea, w, vd1);
            }
        }
        #pragma unroll
        for (int q = 0; q < 4; ++q) { VD[0][q] = vd0[q] + bv0; VD[1][q] = vd1[q] + bv1; }
        #pragma unroll
        for (int nt = 0; nt < 2; ++nt)
            #pragma unroll
            for (int q = 0; q < 4; ++q)
                z1b[4 * g + q][nt * 16 + r] = (f16)VD[nt][q];
        WBAR();
        va = *(const f16x8*)((const char*)z1b + (size_t)r * 64 + g * 16);
    }
    __syncthreads();     // es reads drained -> es region may be reused

    // ---- NOW overwrite the es region: h0 (spine, cols 34..63), rin0 (head, 0..3)
    if (wid == 0) {
        #pragma unroll
        for (int nt = 0; nt < 2; ++nt)
            #pragma unroll
            for (int q = 0; q < 4; ++q)
                x16[4 * g + q][34 + nt * 16 + r] = (f16)hD[nt][q];  // nt1 r>=14 -> scratch
    } else {
        if (l < 16) {
            #pragma unroll
            for (int d = 0; d < 4; ++d)
                x16[l][d] = (f16)r0v[d];
        }
    }
    // spine's A_1 reads its own h0 writes (same-wave order); head's rin0 is
    // consumed by B_1 only after the P1-end __syncthreads -> no barrier needed.

    // ---- 12-step pipelined recurrence ------------------------------------------
    float py1 = 0.f, py2 = 0.f, py3 = 0.f;   // head's y prefetch
    #pragma unroll 1
    for (int i = 1; i <= 12; ++i) {
        // P1: spine A_i  ||  head C/D/E of step i-1
        if (wid == 0) {
            // A: gate = sig([h|V] @ Wg.T + bg); enh -> x16 cols 4..33
            // (cols 32,33 stale values are zero-weighted in gf[0])
            const f16x8 xhg = *(const f16x8*)((const char*)x16 + (size_t)r * 144 + 64 + g * 16);
            f32x4 gd0 = MFMA16(xhg, gf[0][0], kz); gd0 = MFMA16(va, gf[1][0], gd0);
            f32x4 gd1 = MFMA16(xhg, gf[0][1], kz); gd1 = MFMA16(va, gf[1][1], gd1);
            #pragma unroll
            for (int nt = 0; nt < 2; ++nt)
                #pragma unroll
                for (int q = 0; q < 4; ++q) {
                    const float a  = (nt ? gd1[q] : gd0[q]) + bgv[nt];
                    const float gt = fast_sig(a);
                    const float enh = gt * hD[nt][q] + (1.f - gt) * VD[nt][q];
                    const int j = nt * 16 + r;
                    if (j < 30) x16[4 * g + q][4 + j] = (f16)enh;
                }
        } else if (i > 1) {
            const int s = i - 1;
            const float se = (float)s * (1.f / 12.f);
            // C: z1 = relu([h_s|se] @ Wf1.T + bf1)  (concurrent cols 32/33 writes
            // by spine A are finite f16 and zero-weighted in f1f -> safe)
            {
                const f16x8 hn = *(const f16x8*)((const char*)x16 + (size_t)r * 144 + 64 + g * 16);
                f32x4 d0 = MFMA16(hn, f1f[0], kz);
                f32x4 d1 = MFMA16(hn, f1f[1], kz);
                #pragma unroll
                for (int nt = 0; nt < 2; ++nt)
                    #pragma unroll
                    for (int q = 0; q < 4; ++q) {
                        const float z = fmaxf((nt ? d1[q] : d0[q]) + bf1v[nt] + se * wf1se[nt], 0.f);
                        z1b[4 * g + q][nt * 16 + r] = (f16)z;
                    }
            }
            WBAR();
            // D: z2 = relu(z1 @ Wf2.T + bf2) -> z1b cols 0..15
            {
                const f16x8 z1a = *(const f16x8*)((const char*)z1b + (size_t)r * 64 + g * 16);
                f32x4 d = MFMA16(z1a, f2f, kz);
                #pragma unroll
                for (int q = 0; q < 4; ++q)
                    z1b[4 * g + q][r] = (f16)fmaxf(d[q] + bf2v, 0.f);
            }
            WBAR();
            // E: out_s = z2 @ Wf3.T + bf3; rin_{s+1} = [y[:,s,1:4], out_s]
            {
                const f16x8 z2a = *(const f16x8*)((const char*)z1b + (size_t)r * 64 + g * 16);
                f32x4 od = MFMA16(z2a, f3f, kz);
                if (r == 0) {
                    #pragma unroll
                    for (int q = 0; q < 4; ++q) {
                        const float o = od[q] + bf3v;
                        out[(size_t)(s - 1) * NB + bw + 4 * g + q] = o;
                        x16[4 * g + q][3] = (f16)o;
                    }
                }
            }
            if (l < 16) {
                x16[l][0] = (f16)py1;
                x16[l][1] = (f16)py2;
                x16[l][2] = (f16)py3;
            }
        }
        __syncthreads();   // h_{i-1}+enh_i+rin_i all settled for B_i

        // P2: spine B_i  ||  head y-prefetch for step i
        if (wid == 0) {
            const f16x8 xa0 = *(const f16x8*)((const char*)x16 + (size_t)r * 144 + g * 16);
            const f16x8 xa1 = *(const f16x8*)((const char*)x16 + (size_t)r * 144 + 64 + g * 16);
            f32x4 ld[8];
            #pragma unroll
            for (int tq = 0; tq < 8; ++tq) {
                ld[tq] = MFMA16(xa0, lf[0][tq], kz);
                ld[tq] = MFMA16(xa1, lf[1][tq], ld[tq]);
            }
            #pragma unroll
            for (int jh = 0; jh < 2; ++jh)
                #pragma unroll
                for (int q = 0; q < 4; ++q) {
                    const float ii = fast_sig (ld[0 + jh][q] + bl[0 + jh]);
                    const float ff = fast_sig (ld[2 + jh][q] + bl[2 + jh]);
                    const float gg = fast_tanh(ld[4 + jh][q] + bl[4 + jh]);
                    const float oo = fast_sig (ld[6 + jh][q] + bl[6 + jh]);
                    const float cn = ff * c[jh][q] + ii * gg;
                    c[jh][q] = cn;
                    const float hn = oo * fast_tanh(cn);
                    hD[jh][q] = hn;
                    x16[4 * g + q][34 + jh * 16 + r] = (f16)hn;  // jh1 r>=14 -> scratch
                }
        } else {
            if (l < 16) {
                const float* yp = y + (size_t)(bw + l) * 52 + (size_t)i * 4;
                py1 = yp[1]; py2 = yp[2]; py3 = yp[3];
            }
        }
        __syncthreads();   // h_i visible for head's CDE_i and spine's A_{i+1}
    }

    // ---- epilogue: head finishes C/D/E of step 12
    if (wid == 1) {
        const float se = 1.0f;
        {
            const f16x8 hn = *(const f16x8*)((const char*)x16 + (size_t)r * 144 + 64 + g * 16);
            f32x4 d0 = MFMA16(hn, f1f[0], kz);
            f32x4 d1 = MFMA16(hn, f1f[1], kz);
            #pragma unroll
            for (int nt = 0; nt < 2; ++nt)
                #pragma unroll
                for (int q = 0; q < 4; ++q) {
                    const float z = fmaxf((nt ? d1[q] : d0[q]) + bf1v[nt] + se * wf1se[nt], 0.f);
                    z1b[4 * g + q][nt * 16 + r] = (f16)z;
                }
        }
        WBAR();
        {
            const f16x8 z1a = *(const f16x8*)((const char*)z1b + (size_t)r * 64 + g * 16);
            f32x4 d = MFMA16(z1a, f2f, kz);
            #pragma unroll
            for (int q = 0; q < 4; ++q)
                z1b[4 * g + q][r] = (f16)fmaxf(d[q] + bf2v, 0.f);
        }
        WBAR();
        {
            const f16x8 z2a = *(const f16x8*)((const char*)z1b + (size_t)r * 64 + g * 16);
            f32x4 od = MFMA16(z2a, f3f, kz);
            if (r == 0) {
                #pragma unroll
                for (int q = 0; q < 4; ++q)
                    out[(size_t)11 * NB + bw + 4 * g + q] = od[q] + bf3v;
            }
        }
    }
}

extern "C" void kernel_launch(void* const* d_in, const int* in_sizes, int n_in,
                              void* d_out, int out_size, void* d_ws, size_t ws_size,
                              hipStream_t stream) {
    (void)in_sizes; (void)n_in; (void)out_size;
    // 0 batch_ids, 1 y, 2 encoder_outputs, 3 hidden, 4 Wq, 5 bq, 6 Wk, 7 bk,
    // 8 Wv, 9 bv, 10 Wsa1, 11 bsa1, 12 Wsa2, 13 bsa2, 14 Wg, 15 bg,
    // 16 Wf1, 17 bf1, 18 Wf2, 19 bf2, 20 Wf3, 21 bf3, 22 W_ih, 23 b_ih,
    // 24 W_hh, 25 b_hh.  (Wq/bq/Wk/bk/Wsa* dead: softmax over size-1 axis == 1)
    const float* enc = (const float*)d_in[2];
    const size_t es_bytes = (size_t)NB * 60 * sizeof(float);
    float* es = (ws_size >= es_bytes) ? (float*)d_ws : nullptr;

    if (es) {
        es_kernel<<<dim3(NB * 15 / 256), dim3(256), 0, stream>>>(enc, es);
    }
    decoder_kernel<<<dim3(NB / 16), dim3(128), 0, stream>>>(
        (const float*)d_in[1],  enc, es, (const float*)d_in[3],
        (const float*)d_in[8],  (const float*)d_in[9],
        (const float*)d_in[14], (const float*)d_in[15],
        (const float*)d_in[16], (const float*)d_in[17],
        (const float*)d_in[18], (const float*)d_in[19],
        (const float*)d_in[20], (const float*)d_in[21],
        (const float*)d_in[22], (const float*)d_in[23],
        (const float*)d_in[24], (const float*)d_in[25],
        (float*)d_out);
}